// Round 6
// baseline (243.480 us; speedup 1.0000x reference)
//
#include <hip/hip_runtime.h>

// Problem constants
#define NB 128
#define NL 1024
#define NE 512
#define NA 512
#define ND 512

typedef __attribute__((ext_vector_type(8))) short short8;
typedef __attribute__((ext_vector_type(4))) float f32x4;

static __device__ __forceinline__ unsigned short f2bf(float f) {
  unsigned int u = __float_as_uint(f);
  u += 0x7FFF + ((u >> 16) & 1);   // round-to-nearest-even
  return (unsigned short)(u >> 16);
}

// async global->LDS, 16B per lane (wave-uniform LDS base + lane*16)
static __device__ __forceinline__ void async_cp16(const void* g, void* l) {
  __builtin_amdgcn_global_load_lds(
      (const __attribute__((address_space(1))) void*)g,
      (__attribute__((address_space(3))) void*)l, 16, 0, 0);
}

// ---------------------------------------------------------------------------
// Kernel 1 (merged): blocks 0..63 pack W_enc -> bf16 MFMA B-fragment order;
// blocks 64..191 compute att2[b][a] = dec[b]@W_dec[:,a] + b_dec[a] + b_enc[a].
// Bpack layout: [ki=0..15][nf=0..31][lane=0..63][j=0..7]  (chunk ki contiguous)
__global__ void k_prep(const float* __restrict__ W_enc,
                       unsigned short* __restrict__ Bpack,
                       const float* __restrict__ dec,
                       const float* __restrict__ Wdec,
                       const float* __restrict__ b_enc,
                       const float* __restrict__ b_dec,
                       float* __restrict__ att2) {
  int blk = blockIdx.x;
  int tid = threadIdx.x;  // 512
  if (blk < 64) {
    int t = blk * 512 + tid;  // 0..32767
    int lane = t & 63;
    int rest = t >> 6;        // rest = ki*32 + nf
    int nf = rest & 31;
    int ki = rest >> 5;
    int col = nf * 16 + (lane & 15);
    int kbase = ki * 32 + (lane >> 4) * 8;
    short8 v;
#pragma unroll
    for (int j = 0; j < 8; ++j)
      v[j] = (short)f2bf(W_enc[(kbase + j) * NA + col]);
    *reinterpret_cast<short8*>(Bpack + (long)t * 8) = v;
  } else {
    int b = blk - 64;
    int a = tid;
    float acc = b_enc[a] + b_dec[a];
    const float* drow = dec + b * ND;
#pragma unroll 4
    for (int d = 0; d < ND; ++d)
      acc += drow[d] * Wdec[d * NA + a];
    att2[b * NA + a] = acc;
  }
}

// ---------------------------------------------------------------------------
// Kernel 2: persistent fused scores GEMM. Grid=256 (1 block/CU), 512 thr
// (8 waves). Each block owns 8 consecutive M-tiles of 64 rows.
// A tile in LDS fragment order (linear, conflict-free); next tile's A
// prefetched into VGPRs at step 13 of the current K-loop, written to LDS at
// the tile boundary (staging latency hidden under MFMAs).
// B: wave-private depth-3 LDS ring via global_load_lds, counted vmcnt,
// stream continues seamlessly across tiles.
// Epilogue per tile: relu(acc+att2)*W_full col-reduced per wave ->
// global partials att_p[tile][wave][64] (summed later in softmax).
__global__ __launch_bounds__(512, 2) void k_scores(
    const float* __restrict__ enc, const unsigned short* __restrict__ Bpack,
    const float* __restrict__ att2g, const float* __restrict__ wfull,
    float* __restrict__ att_p) {
  extern __shared__ char smem[];
  const int t = threadIdx.x;
  const int lane = t & 63;
  const int wave = t >> 6;
  const int l15 = lane & 15;
  const int lq = lane >> 4;
  const int blk = blockIdx.x;   // 0..255

  float wfr[4];
#pragma unroll
  for (int cf = 0; cf < 4; ++cf) wfr[cf] = wfull[wave * 64 + cf * 16 + l15];

  float4 fA[16];     // A prefetch for next tile (static indexing only)
  float a2r[4];      // att2 prefetch for current tile's epilogue
  int cso = 0;       // LDS byte offset of current consume slot (0/32768/65536)
  int iso = 65536;   // LDS byte offset of issue slot (= consume+2 mod 3)

#define B_ISSUE(SRCKI, SLOTBYTE)                                              \
  {                                                                           \
    const unsigned short* bsrc =                                              \
        Bpack + (((long)(SRCKI)*32 + wave * 4) * 64 + lane) * 8;              \
    char* bdst = smem + 65536 + (SLOTBYTE) + wave * 4096 + lane * 16;         \
    async_cp16(bsrc, bdst);                                                   \
    async_cp16(bsrc + 512, bdst + 1024);                                      \
    async_cp16(bsrc + 1024, bdst + 2048);                                     \
    async_cp16(bsrc + 1536, bdst + 3072);                                     \
  }

#define A_LOAD(ROW0)                                                          \
  {                                                                           \
    _Pragma("unroll") for (int it = 0; it < 8; ++it) {                        \
      int fr = it * 8 + wave;                                                 \
      int row = (fr >> 4) * 16 + l15;                                         \
      int k0 = (fr & 15) * 32 + lq * 8;                                       \
      const float4* p =                                                       \
          reinterpret_cast<const float4*>(enc + ((long)(ROW0) + row) * NE + k0); \
      fA[it * 2] = p[0];                                                      \
      fA[it * 2 + 1] = p[1];                                                  \
    }                                                                         \
  }

#define A_WRITE()                                                             \
  {                                                                           \
    _Pragma("unroll") for (int it = 0; it < 8; ++it) {                        \
      int fr = it * 8 + wave;                                                 \
      float4 x0 = fA[it * 2], x1 = fA[it * 2 + 1];                            \
      short8 o;                                                               \
      o[0] = (short)f2bf(x0.x); o[1] = (short)f2bf(x0.y);                     \
      o[2] = (short)f2bf(x0.z); o[3] = (short)f2bf(x0.w);                     \
      o[4] = (short)f2bf(x1.x); o[5] = (short)f2bf(x1.y);                     \
      o[6] = (short)f2bf(x1.z); o[7] = (short)f2bf(x1.w);                     \
      *reinterpret_cast<short8*>(smem + fr * 1024 + lane * 16) = o;           \
    }                                                                         \
  }

#define A2_LOAD(TG)                                                           \
  {                                                                           \
    int bb = (int)((TG) >> 4);                                                \
    _Pragma("unroll") for (int cf = 0; cf < 4; ++cf)                          \
        a2r[cf] = att2g[bb * NA + wave * 64 + cf * 16 + l15];                 \
  }

#define STEP(KI, VMSTR, DOISS)                                                \
  {                                                                           \
    if (DOISS) B_ISSUE(((KI) + 2) & 15, iso);                                 \
    asm volatile("s_waitcnt vmcnt(" VMSTR ")" ::: "memory");                  \
    const char* bbase = smem + 65536 + cso + wave * 4096 + lane * 16;         \
    short8 bv0 = *reinterpret_cast<const short8*>(bbase);                     \
    short8 bv1 = *reinterpret_cast<const short8*>(bbase + 1024);              \
    short8 bv2 = *reinterpret_cast<const short8*>(bbase + 2048);              \
    short8 bv3 = *reinterpret_cast<const short8*>(bbase + 3072);              \
    const char* abase = smem + (KI)*1024 + lane * 16;                         \
    short8 av0 = *reinterpret_cast<const short8*>(abase);                     \
    short8 av1 = *reinterpret_cast<const short8*>(abase + 16384);             \
    short8 av2 = *reinterpret_cast<const short8*>(abase + 32768);             \
    short8 av3 = *reinterpret_cast<const short8*>(abase + 49152);             \
    acc[0][0] = __builtin_amdgcn_mfma_f32_16x16x32_bf16(av0, bv0, acc[0][0], 0, 0, 0); \
    acc[0][1] = __builtin_amdgcn_mfma_f32_16x16x32_bf16(av0, bv1, acc[0][1], 0, 0, 0); \
    acc[0][2] = __builtin_amdgcn_mfma_f32_16x16x32_bf16(av0, bv2, acc[0][2], 0, 0, 0); \
    acc[0][3] = __builtin_amdgcn_mfma_f32_16x16x32_bf16(av0, bv3, acc[0][3], 0, 0, 0); \
    acc[1][0] = __builtin_amdgcn_mfma_f32_16x16x32_bf16(av1, bv0, acc[1][0], 0, 0, 0); \
    acc[1][1] = __builtin_amdgcn_mfma_f32_16x16x32_bf16(av1, bv1, acc[1][1], 0, 0, 0); \
    acc[1][2] = __builtin_amdgcn_mfma_f32_16x16x32_bf16(av1, bv2, acc[1][2], 0, 0, 0); \
    acc[1][3] = __builtin_amdgcn_mfma_f32_16x16x32_bf16(av1, bv3, acc[1][3], 0, 0, 0); \
    acc[2][0] = __builtin_amdgcn_mfma_f32_16x16x32_bf16(av2, bv0, acc[2][0], 0, 0, 0); \
    acc[2][1] = __builtin_amdgcn_mfma_f32_16x16x32_bf16(av2, bv1, acc[2][1], 0, 0, 0); \
    acc[2][2] = __builtin_amdgcn_mfma_f32_16x16x32_bf16(av2, bv2, acc[2][2], 0, 0, 0); \
    acc[2][3] = __builtin_amdgcn_mfma_f32_16x16x32_bf16(av2, bv3, acc[2][3], 0, 0, 0); \
    acc[3][0] = __builtin_amdgcn_mfma_f32_16x16x32_bf16(av3, bv0, acc[3][0], 0, 0, 0); \
    acc[3][1] = __builtin_amdgcn_mfma_f32_16x16x32_bf16(av3, bv1, acc[3][1], 0, 0, 0); \
    acc[3][2] = __builtin_amdgcn_mfma_f32_16x16x32_bf16(av3, bv2, acc[3][2], 0, 0, 0); \
    acc[3][3] = __builtin_amdgcn_mfma_f32_16x16x32_bf16(av3, bv3, acc[3][3], 0, 0, 0); \
    cso = (cso == 65536) ? 0 : cso + 32768;                                   \
    iso = (iso == 65536) ? 0 : iso + 32768;                                   \
  }

#define EPI(TG)                                                               \
  {                                                                           \
    float px[4][4];                                                           \
    _Pragma("unroll") for (int rt = 0; rt < 4; ++rt)                          \
        _Pragma("unroll") for (int r = 0; r < 4; ++r) px[rt][r] = 0.f;        \
    _Pragma("unroll") for (int cf = 0; cf < 4; ++cf) {                        \
      float a2 = a2r[cf], w = wfr[cf];                                        \
      _Pragma("unroll") for (int rt = 0; rt < 4; ++rt)                        \
          _Pragma("unroll") for (int r = 0; r < 4; ++r) {                     \
        float v = acc[rt][cf][r] + a2;                                        \
        px[rt][r] += fmaxf(v, 0.f) * w;                                       \
      }                                                                       \
    }                                                                         \
    _Pragma("unroll") for (int rt = 0; rt < 4; ++rt)                          \
        _Pragma("unroll") for (int r = 0; r < 4; ++r) {                       \
      float p = px[rt][r];                                                    \
      p += __shfl_xor(p, 1);                                                  \
      p += __shfl_xor(p, 2);                                                  \
      p += __shfl_xor(p, 4);                                                  \
      p += __shfl_xor(p, 8);                                                  \
      px[rt][r] = p;                                                          \
    }                                                                         \
    if (l15 == 0) {                                                           \
      _Pragma("unroll") for (int rt = 0; rt < 4; ++rt) {                      \
        float4 st = {px[rt][0], px[rt][1], px[rt][2], px[rt][3]};             \
        *reinterpret_cast<float4*>(                                           \
            att_p + (TG)*512 + wave * 64 + rt * 16 + lq * 4) = st;            \
      }                                                                       \
    }                                                                         \
    _Pragma("unroll") for (int rt = 0; rt < 4; ++rt)                          \
        _Pragma("unroll") for (int cf = 0; cf < 4; ++cf)                      \
            acc[rt][cf] = (f32x4){0.f, 0.f, 0.f, 0.f};                        \
  }

  // ---- prologue: tile 0 ----
  B_ISSUE(0, 0);
  A_LOAD((long)blk * 8 * 64);
  B_ISSUE(1, 32768);
  A_WRITE();          // compiler waits fA; chunk0/1 still counted
  __syncthreads();    // drains vmcnt: chunk0,1 + A in LDS

  f32x4 acc[4][4];
#pragma unroll
  for (int rt = 0; rt < 4; ++rt)
#pragma unroll
    for (int cf = 0; cf < 4; ++cf) acc[rt][cf] = (f32x4){0.f, 0.f, 0.f, 0.f};

#pragma unroll 1
  for (int T = 0; T < 7; ++T) {
    const long tg = (long)blk * 8 + T;
#pragma unroll
    for (int ki = 0; ki < 13; ++ki) STEP(ki, "8", true);
    // prefetch next tile's A + this tile's att2 (adds 20 outstanding loads)
    A_LOAD((tg + 1) * 64);
    A2_LOAD(tg);
    STEP(13, "28", true);
    STEP(14, "28", true);
    STEP(15, "8", true);
    EPI(tg);
    __syncthreads();   // all waves done reading A; drains in-flight chunks
    A_WRITE();         // stage tile T+1's A fragments
    __syncthreads();
  }
  {  // last tile (peeled): no A prefetch, drain tail
    const long tg = (long)blk * 8 + 7;
#pragma unroll
    for (int ki = 0; ki < 13; ++ki) STEP(ki, "8", true);
    A2_LOAD(tg);
    STEP(13, "12", true);
    STEP(14, "8", false);
    STEP(15, "0", false);
    EPI(tg);
  }
#undef STEP
#undef EPI
#undef A_LOAD
#undef A_WRITE
#undef A2_LOAD
#undef B_ISSUE
}

// ---------------------------------------------------------------------------
// Kernel 3: softmax over L=1024 per batch row; sums the 8 per-wave partials.
__global__ void k_softmax(const float* __restrict__ att_p,
                          float* __restrict__ alpha) {
  int b = blockIdx.x;
  int t = threadIdx.x;  // 256
  float v[4];
#pragma unroll
  for (int j = 0; j < 4; ++j) {
    int l = t + j * 256;
    long base = ((long)b * 16 + (l >> 6)) * 512 + (l & 63);
    float s = 0.f;
#pragma unroll
    for (int w = 0; w < 8; ++w) s += att_p[base + w * 64];
    v[j] = s;
  }
  float m = fmaxf(fmaxf(v[0], v[1]), fmaxf(v[2], v[3]));
#pragma unroll
  for (int off = 1; off < 64; off <<= 1) m = fmaxf(m, __shfl_xor(m, off));
  __shared__ float rm[4];
  int lane = t & 63, w = t >> 6;
  if (lane == 0) rm[w] = m;
  __syncthreads();
  m = fmaxf(fmaxf(rm[0], rm[1]), fmaxf(rm[2], rm[3]));
  float e0 = expf(v[0] - m), e1 = expf(v[1] - m);
  float e2 = expf(v[2] - m), e3 = expf(v[3] - m);
  float s = e0 + e1 + e2 + e3;
#pragma unroll
  for (int off = 1; off < 64; off <<= 1) s += __shfl_xor(s, off);
  __shared__ float rs[4];
  if (lane == 0) rs[w] = s;
  __syncthreads();
  s = rs[0] + rs[1] + rs[2] + rs[3];
  float inv = 1.f / s;
  float* arow = alpha + b * NL;
  arow[t] = e0 * inv;
  arow[t + 256] = e1 * inv;
  arow[t + 512] = e2 * inv;
  arow[t + 768] = e3 * inv;
}

// ---------------------------------------------------------------------------
// Kernel 4: partial weighted sum. Grid = 128 b * 16 l-chunks, 128 threads.
__global__ void k_wpart(const float* __restrict__ enc,
                        const float* __restrict__ alpha,
                        float* __restrict__ part) {
  int bid = blockIdx.x;          // 0..2047
  int b = bid >> 4, lc = bid & 15;
  int t = threadIdx.x;           // 0..127
  const float* base = enc + ((long)b * NL + lc * 64) * NE;
  const float* al = alpha + b * NL + lc * 64;
  float4 s = {0.f, 0.f, 0.f, 0.f};
#pragma unroll 4
  for (int l = 0; l < 64; ++l) {
    float a = al[l];
    const float4 x = *reinterpret_cast<const float4*>(base + (long)l * NE + t * 4);
    s.x += a * x.x;
    s.y += a * x.y;
    s.z += a * x.z;
    s.w += a * x.w;
  }
  *reinterpret_cast<float4*>(part + (long)bid * NE + t * 4) = s;
}

// ---------------------------------------------------------------------------
// Kernel 5: reduce 16 l-chunk partials -> weighted [B,E] into d_out.
__global__ void k_wreduce(const float* __restrict__ part,
                          float* __restrict__ outw) {
  int g = blockIdx.x * 256 + threadIdx.x;  // 0..65535
  int b = g >> 9, e = g & 511;
  float s = 0.f;
#pragma unroll
  for (int lc = 0; lc < 16; ++lc) s += part[(long)(b * 16 + lc) * NE + e];
  outw[g] = s;
}

// ---------------------------------------------------------------------------
extern "C" void kernel_launch(void* const* d_in, const int* in_sizes, int n_in,
                              void* d_out, int out_size, void* d_ws, size_t ws_size,
                              hipStream_t stream) {
  const float* enc    = (const float*)d_in[0];  // [B,L,E]
  const float* dec    = (const float*)d_in[1];  // [B,D]
  const float* W_enc  = (const float*)d_in[2];  // [E,A]
  const float* b_enc  = (const float*)d_in[3];  // [A]
  const float* W_dec  = (const float*)d_in[4];  // [D,A]
  const float* b_dec  = (const float*)d_in[5];  // [A]
  const float* W_full = (const float*)d_in[6];  // [A]
  // d_in[7] = b_full: cancels in softmax, unused.

  float* out = (float*)d_out;
  float* weighted = out;                 // [B,E] = 65536
  float* alpha = out + NB * NE;          // [B,L] = 131072

  char* ws = (char*)d_ws;
  float* att2          = (float*)ws;                                   // 256 KB
  unsigned short* Bpk  = (unsigned short*)(ws + (256 << 10));          // 512 KB
  float* att_p         = (float*)(ws + (768 << 10));                   // 4 MB
  float* part          = (float*)(ws + (4864 << 10));                  // 4 MB

  hipLaunchKernelGGL(k_prep, dim3(192), dim3(512), 0, stream,
                     W_enc, Bpk, dec, W_dec, b_enc, b_dec, att2);
  hipLaunchKernelGGL(k_scores, dim3(256), dim3(512), 163840, stream,
                     enc, Bpk, att2, W_full, att_p);
  hipLaunchKernelGGL(k_softmax, dim3(NB), dim3(256), 0, stream, att_p, alpha);
  hipLaunchKernelGGL(k_wpart, dim3(NB * 16), dim3(128), 0, stream, enc, alpha, part);
  hipLaunchKernelGGL(k_wreduce, dim3(NB * NE / 256), dim3(256), 0, stream, part, weighted);
}